// Round 9
// baseline (546.613 us; speedup 1.0000x reference)
//
#include <hip/hip_runtime.h>
#include <math.h>

#define B_ 16
#define P_ 19248
#define C_ 81
#define O_ 32
#define POS_TH 0.5f
#define NEG_TH 0.4f
#define BT_BPB 76            // ceil(P_/256) best_truth blocks per batch
#define NJ 38                // ceil(P_/512) per-thread elements in k_ohem

__device__ __forceinline__ float sl1(float x) {
    float d = fabsf(x);
    return (d < 1.0f) ? 0.5f * d * d : d - 0.5f;
}

__device__ __forceinline__ float iou_gt_prior(float4 t, float4 pr) {
    float px1 = pr.x - pr.z * 0.5f;
    float py1 = pr.y - pr.w * 0.5f;
    float px2 = pr.x + pr.z * 0.5f;
    float py2 = pr.y + pr.w * 0.5f;
    float ltx = fmaxf(t.x, px1), lty = fmaxf(t.y, py1);
    float rbx = fminf(t.z, px2), rby = fminf(t.w, py2);
    float iw = fmaxf(rbx - ltx, 0.0f), ih = fmaxf(rby - lty, 0.0f);
    float inter = iw * ih;
    float area_t = (t.z - t.x) * (t.w - t.y);
    float area_p = (px2 - px1) * (py2 - py1);
    return inter / (area_t + area_p - inter);
}

// ---- parallel threshold pick (512 threads, 8 waves) ----
// Find bin d: sum_{j>d} h[j] < kk <= sum_{j>=d} h[j]. -> *s_bin, residual -> *s_kk.
template <int PER>
__device__ __forceinline__ void pick_top(const int* __restrict__ h, int kk, int tid,
                                         int* s_bin, int* s_kk, int* wsum) {
    const int lane = tid & 63, wid = tid >> 6;
    const int base = tid * PER;
    int v[PER]; int s = 0;
    #pragma unroll
    for (int j = 0; j < PER; ++j) { v[j] = h[base + j]; s += v[j]; }
    int x = s;                                  // inclusive suffix scan in wave
    #pragma unroll
    for (int d = 1; d < 64; d <<= 1) {
        int y = __shfl_down(x, d);
        if (lane + d < 64) x += y;
    }
    if (lane == 0) wsum[wid] = x;
    __syncthreads();
    int above = 0;
    #pragma unroll
    for (int w = 0; w < 8; ++w) if (w > wid) above += wsum[w];
    int T = (x - s) + above;
    if (T < kk && kk <= T + s) {                // exactly one thread true
        int kl = kk - T, cum = 0;
        #pragma unroll
        for (int j = PER - 1; j >= 0; --j) {
            if (cum + v[j] >= kl) { *s_bin = base + j; *s_kk = kl - cum; break; }
            cum += v[j];
        }
    }
    __syncthreads();
}

// Mirror: cumulative FROM THE BOTTOM (kk-th smallest bin).
template <int PER>
__device__ __forceinline__ void pick_bot(const int* __restrict__ h, int kk, int tid,
                                         int* s_bin, int* s_kk, int* wsum) {
    const int lane = tid & 63, wid = tid >> 6;
    const int base = tid * PER;
    int v[PER]; int s = 0;
    #pragma unroll
    for (int j = 0; j < PER; ++j) { v[j] = h[base + j]; s += v[j]; }
    int x = s;                                  // inclusive prefix scan in wave
    #pragma unroll
    for (int d = 1; d < 64; d <<= 1) {
        int y = __shfl_up(x, d);
        if (lane >= d) x += y;
    }
    if (lane == 63) wsum[wid] = x;
    __syncthreads();
    int below = 0;
    #pragma unroll
    for (int w = 0; w < 8; ++w) if (w < wid) below += wsum[w];
    int T = (x - s) + below;
    if (T < kk && kk <= T + s) {
        int kl = kk - T, cum = 0;
        #pragma unroll
        for (int j = 0; j < PER; ++j) {
            if (cum + v[j] >= kl) { *s_bin = base + j; *s_kk = kl - cum; break; }
            cum += v[j];
        }
    }
    __syncthreads();
}

// Merged matcher. Blocks [0, 512): best_prior (one per (b,o), argmax over P).
// Blocks [512, 512+1216): best_truth (per-prior max/argmax over O gts + label).
__global__ void k_match(const float* __restrict__ priors,
                        const float* __restrict__ gt_boxes,
                        const int* __restrict__ gt_labels,
                        int* __restrict__ best_pr,
                        float* __restrict__ bt_ov,
                        int* __restrict__ bt_ix,
                        int* __restrict__ bt_lab) {
    const int bid = blockIdx.x;
    if (bid < B_ * O_) {
        // ---- best_prior role ----
        int b = bid >> 5, o = bid & 31;
        float4 t = ((const float4*)gt_boxes)[b * O_ + o];
        float bestv = -1.0f; int besti = 0;
        for (int p = threadIdx.x; p < P_; p += blockDim.x) {
            float4 pr = ((const float4*)priors)[p];
            float v = iou_gt_prior(t, pr);
            if (v > bestv) { bestv = v; besti = p; }
        }
        __shared__ float sv[256];
        __shared__ int   si[256];
        sv[threadIdx.x] = bestv; si[threadIdx.x] = besti;
        __syncthreads();
        for (int s = 128; s > 0; s >>= 1) {
            if (threadIdx.x < s) {
                float ov = sv[threadIdx.x + s]; int oi = si[threadIdx.x + s];
                if (ov > sv[threadIdx.x] ||
                    (ov == sv[threadIdx.x] && oi < si[threadIdx.x])) {
                    sv[threadIdx.x] = ov; si[threadIdx.x] = oi;
                }
            }
            __syncthreads();
        }
        if (threadIdx.x == 0) best_pr[b * O_ + o] = si[0];
    } else {
        // ---- best_truth role ----
        int idx = bid - B_ * O_;
        int b = idx / BT_BPB;
        int p = (idx % BT_BPB) * 256 + threadIdx.x;
        __shared__ float4 gt[O_];
        __shared__ int    gl[O_];
        if (threadIdx.x < O_) {
            gt[threadIdx.x] = ((const float4*)gt_boxes)[b * O_ + threadIdx.x];
            gl[threadIdx.x] = gt_labels[b * O_ + threadIdx.x];
        }
        __syncthreads();
        if (p >= P_) return;
        float4 pr = ((const float4*)priors)[p];
        float bestv = -1.0f; int besti = 0;
        for (int o = 0; o < O_; ++o) {
            float v = iou_gt_prior(gt[o], pr);
            if (v > bestv) { bestv = v; besti = o; }
        }
        size_t bp = (size_t)b * P_ + p;
        bt_ov[bp] = bestv;
        bt_ix[bp] = besti;
        bt_lab[bp] = gl[besti];
    }
}

// Force-match (numpy last-wins scatter: serial per batch, by leader lane via
// shfl so loads are parallel) + zero the accumulators consumed downstream.
__global__ void k_force(const int* __restrict__ best_pr,
                        const int* __restrict__ gt_labels,
                        float* __restrict__ bt_ov,
                        int* __restrict__ bt_ix,
                        int* __restrict__ bt_lab,
                        int* __restrict__ num_pos,
                        float* __restrict__ accum,
                        int* __restrict__ done) {
    const int tid = threadIdx.x;          // 512 = 16 batches x 32 gts
    const int b = tid >> 5, o = tid & 31;
    int p  = best_pr[b * O_ + o];
    int ll = gt_labels[b * O_ + o];
    if (tid < B_) num_pos[tid] = 0;
    if (tid == 0) { accum[0] = 0.0f; accum[1] = 0.0f; *done = 0; }
    const int lanebase = tid & 32;        // batch's base lane within the wave
    for (int oo = 0; oo < O_; ++oo) {
        int pp = __shfl(p, lanebase + oo);
        int l2 = __shfl(ll, lanebase + oo);
        if (o == 0) {
            size_t idx = (size_t)b * P_ + pp;
            bt_ov[idx] = 2.0f;
            bt_ix[idx] = oo;
            bt_lab[idx] = l2;
        }
    }
}

// Register-resident main pass: 16 lanes per row, NO LDS, NO barriers.
// Lane e0 of a row loads elements e0+16k (k=0..4) + lane0 takes element 80;
// 4-step shfl_xor group reduction for max and sum-of-exp; row[cls] via
// compile-time cndmask chain + one dynamic shfl. Each wave computes as soon
// as its own loads land; occupancy capped only by VGPR (~32 waves/CU).
__global__ __launch_bounds__(512) void
k_main(const float* __restrict__ loc_data,
       const float* __restrict__ conf_data,
       const float* __restrict__ priors,
       const float* __restrict__ gt_boxes,
       const float* __restrict__ bt_ov,
       const int* __restrict__ bt_ix,
       const int* __restrict__ bt_lab,
       float* __restrict__ lossc,
       float* __restrict__ ce_neg,
       int* __restrict__ num_pos,
       float* __restrict__ accum) {
    const int tid = threadIdx.x;
    const int gid = blockIdx.x * 512 + tid;
    const int row = gid >> 4;             // 16 lanes per row; grid exact
    const int e0  = gid & 15;
    const int lanebase = (tid & 63) & ~15;

    // issue match metadata + row loads early, all independent
    float ov = bt_ov[row];
    int lab  = bt_lab[row];
    const float* rp = conf_data + (size_t)row * C_;
    float v0 = rp[e0];
    float v1 = rp[e0 + 16];
    float v2 = rp[e0 + 32];
    float v3 = rp[e0 + 48];
    float v4 = rp[e0 + 64];
    float v5 = (e0 == 0) ? rp[80] : -INFINITY;

    // group max
    float m = fmaxf(fmaxf(fmaxf(v0, v1), fmaxf(v2, v3)), fmaxf(v4, v5));
    m = fmaxf(m, __shfl_xor(m, 1));
    m = fmaxf(m, __shfl_xor(m, 2));
    m = fmaxf(m, __shfl_xor(m, 4));
    m = fmaxf(m, __shfl_xor(m, 8));

    // group sum of exp
    float s = __expf(v0 - m) + __expf(v1 - m) + __expf(v2 - m) +
              __expf(v3 - m) + __expf(v4 - m) + ((e0 == 0) ? __expf(v5 - m) : 0.0f);
    s += __shfl_xor(s, 1);
    s += __shfl_xor(s, 2);
    s += __shfl_xor(s, 4);
    s += __shfl_xor(s, 8);
    float logZ = m + __logf(s);

    // conf_t classification (row-uniform across the 16-group)
    int conf_t = lab + 1;
    if (ov < POS_TH) conf_t = -1;
    if (ov < NEG_TH) conf_t = 0;
    bool pos = conf_t > 0;
    int cls = pos ? conf_t : 0;

    // fetch row[cls]: static reg select (cls>>4 uniform) + dynamic lane shfl
    int rsel = cls >> 4;
    float sel = v0;
    sel = (rsel == 1) ? v1 : sel;
    sel = (rsel == 2) ? v2 : sel;
    sel = (rsel == 3) ? v3 : sel;
    sel = (rsel == 4) ? v4 : sel;
    sel = (rsel == 5) ? v5 : sel;
    float ccls = __shfl(sel, lanebase + (cls & 15));
    float conf0 = __shfl(v0, lanebase);
    float ce = logZ - ccls;

    if (e0 == 0) {
        float lc = (pos || conf_t < 0) ? 0.0f : (logZ - conf0);
        lossc[row] = lc;
        ce_neg[row] = (conf_t == 0) ? ce : 0.0f;

        if (pos) {
            int b = row / P_;
            int p = row - b * P_;
            int ti = bt_ix[row];
            float4 t = ((const float4*)gt_boxes)[b * O_ + ti];
            float4 pr = ((const float4*)priors)[p];
            float mcx = (t.x + t.z) * 0.5f;
            float mcy = (t.y + t.w) * 0.5f;
            float gx = (mcx - pr.x) / (0.1f * pr.z);
            float gy = (mcy - pr.y) / (0.1f * pr.w);
            float gw = logf((t.z - t.x) / pr.z) / 0.2f;
            float gh = logf((t.w - t.y) / pr.w) / 0.2f;
            float4 ld = ((const float4*)loc_data)[row];
            float sc2 = sl1(ld.x - gx) + sl1(ld.y - gy) + sl1(ld.z - gw) + sl1(ld.w - gh);
            atomicAdd(&accum[0], sc2);
            atomicAdd(&accum[1], ce);
            atomicAdd(&num_pos[b], 1);
        }
    }
}

// One block per batch: element data cached in registers (38/thread), in-LDS
// 1024-bin hist of fb>>21 (monotone, lossc>=0), two refine passes over bits
// 20..10 / 9..0, exact stable-argsort tie-break on fb==V via index radix.
// Last block to finish folds the final scalar reduction and writes out[2].
__global__ __launch_bounds__(512) void
k_ohem(const float* __restrict__ lossc, const float* __restrict__ ce_neg,
       const int* __restrict__ num_pos, const float* __restrict__ accum,
       float* __restrict__ ce_sum, int* __restrict__ done,
       float* __restrict__ out) {
    const int b = blockIdx.x;
    const int tid = threadIdx.x;
    const float* lc = lossc + (size_t)b * P_;
    const float* cn = ce_neg + (size_t)b * P_;
    __shared__ int h[2048];
    __shared__ int wsum[8];
    __shared__ int s_bin, s_kk;
    __shared__ float red[512];

    int k = 3 * num_pos[b];
    if (k > P_ - 1) k = P_ - 1;

    float result = 0.0f;
    if (k > 0) {
        unsigned int fb[NJ]; float cv[NJ];
        #pragma unroll
        for (int j = 0; j < NJ; ++j) {
            int i = tid + j * 512;
            bool valid = (i < P_);
            fb[j] = valid ? __float_as_uint(lc[i]) : 0xFFFFFFFFu;
            cv[j] = valid ? cn[i] : 0.0f;
        }
        // round 0: 1024-bin hist of fb>>21
        for (int i = tid; i < 2048; i += 512) h[i] = 0;
        __syncthreads();
        #pragma unroll
        for (int j = 0; j < NJ; ++j) atomicAdd(&h[fb[j] >> 21], 1);
        __syncthreads();
        pick_top<2>(h, k, tid, &s_bin, &s_kk, wsum);
        const unsigned int T = (unsigned int)s_bin;
        int kk = s_kk;

        // pass A: sum ce for bins > T; hist bits 20..10 of bin==T
        for (int i = tid; i < 2048; i += 512) h[i] = 0;
        __syncthreads();
        float sum = 0.0f;
        #pragma unroll
        for (int j = 0; j < NJ; ++j) {
            unsigned int bin = fb[j] >> 21;
            if (bin > T) sum += cv[j];                 // sentinel adds 0
            else if (bin == T) atomicAdd(&h[(fb[j] >> 10) & 2047], 1);
        }
        __syncthreads();
        pick_top<4>(h, kk, tid, &s_bin, &s_kk, wsum);
        const unsigned int pre21 = (T << 11) | (unsigned int)s_bin;
        kk = s_kk;

        // pass B: hist bits 9..0 of elements matching top 22 bits
        for (int i = tid; i < 1024; i += 512) h[i] = 0;
        __syncthreads();
        #pragma unroll
        for (int j = 0; j < NJ; ++j)
            if ((fb[j] >> 10) == pre21) atomicAdd(&h[fb[j] & 1023], 1);
        __syncthreads();
        pick_top<2>(h, kk, tid, &s_bin, &s_kk, wsum);
        const unsigned int V = (pre21 << 10) | (unsigned int)s_bin;
        const int ee = h[s_bin];
        kk = s_kk;

        if (kk == ee) {
            #pragma unroll
            for (int j = 0; j < NJ; ++j)
                if ((fb[j] >> 21) == T && fb[j] >= V) sum += cv[j];
        } else {
            // kk smallest-index elements with fb == V (stable argsort ties)
            for (int i = tid; i < 512; i += 512) h[i] = 0;
            __syncthreads();
            #pragma unroll
            for (int j = 0; j < NJ; ++j)
                if (fb[j] == V) atomicAdd(&h[(tid + j * 512) >> 6], 1);
            __syncthreads();
            pick_bot<1>(h, kk, tid, &s_bin, &s_kk, wsum);
            const int d6 = s_bin;
            kk = s_kk;
            h[tid] = 0;
            __syncthreads();
            #pragma unroll
            for (int j = 0; j < NJ; ++j) {
                int i = tid + j * 512;
                if (fb[j] == V && (i >> 6) == d6) atomicAdd(&h[i & 63], 1);
            }
            __syncthreads();
            pick_bot<1>(h, kk, tid, &s_bin, &s_kk, wsum);
            const int Istar = (d6 << 6) | s_bin;
            #pragma unroll
            for (int j = 0; j < NJ; ++j) {
                int i = tid + j * 512;
                if ((fb[j] >> 21) == T && (fb[j] > V || (fb[j] == V && i <= Istar)))
                    sum += cv[j];
            }
        }

        red[tid] = sum;
        __syncthreads();
        for (int s = 256; s > 0; s >>= 1) {
            if (tid < s) red[tid] += red[tid + s];
            __syncthreads();
        }
        result = red[0];
    }

    if (tid == 0) {
        ce_sum[b] = result;
        __threadfence();
        int old = atomicAdd(done, 1);
        if (old == B_ - 1) {                  // last block folds the output
            __threadfence();
            int tp = 0; float ns = 0.0f;
            for (int bb = 0; bb < B_; ++bb) { tp += num_pos[bb]; ns += ce_sum[bb]; }
            float inv = 1.0f / (float)tp;
            out[0] = accum[0] * 1.5f * inv;   // BBOX_ALPHA
            out[1] = (accum[1] + ns) * inv;   // CONF_ALPHA
        }
    }
}

extern "C" void kernel_launch(void* const* d_in, const int* in_sizes, int n_in,
                              void* d_out, int out_size, void* d_ws, size_t ws_size,
                              hipStream_t stream) {
    const float* loc    = (const float*)d_in[0];
    const float* conf   = (const float*)d_in[1];
    const float* priors = (const float*)d_in[2];
    const float* gtb    = (const float*)d_in[3];
    const int*   gtl    = (const int*)d_in[4];
    float* out = (float*)d_out;

    const size_t BP = (size_t)B_ * P_;
    float* W = (float*)d_ws;
    float* bt_ov   = W;
    float* lossc   = W + BP;
    float* ce_neg  = W + 2 * BP;
    int*   bt_ix   = (int*)(W + 3 * BP);
    int*   bt_lab  = (int*)(W + 4 * BP);
    int*   best_pr = (int*)(W + 5 * BP);
    int*   num_pos = best_pr + B_ * O_;
    float* ce_sum  = (float*)(num_pos + B_);
    float* accum   = ce_sum + B_;
    int*   done    = (int*)(accum + 2);

    hipLaunchKernelGGL(k_match, dim3(B_ * O_ + B_ * BT_BPB), dim3(256), 0, stream,
                       priors, gtb, gtl, best_pr, bt_ov, bt_ix, bt_lab);
    hipLaunchKernelGGL(k_force, dim3(1), dim3(512), 0, stream,
                       best_pr, gtl, bt_ov, bt_ix, bt_lab, num_pos, accum, done);
    hipLaunchKernelGGL(k_main, dim3((int)(BP * 16 / 512)), dim3(512), 0, stream,
                       loc, conf, priors, gtb, bt_ov, bt_ix, bt_lab,
                       lossc, ce_neg, num_pos, accum);
    hipLaunchKernelGGL(k_ohem, dim3(B_), dim3(512), 0, stream,
                       lossc, ce_neg, num_pos, accum, ce_sum, done, out);
}

// Round 10
// 121.112 us; speedup vs baseline: 4.5133x; 4.5133x over previous
//
#include <hip/hip_runtime.h>
#include <math.h>

#define B_ 16
#define P_ 19248
#define C_ 81
#define O_ 32
#define POS_TH 0.5f
#define NEG_TH 0.4f
#define RPB 128              // rows per k_main tile; B_*P_ = 307968 = 2406*128
#define TPB 512              // threads per k_main block (8 waves), 4 threads/row
#define PQ  4812             // P_/4: priors per best_prior quarter-block
#define BP_BLK (B_ * O_ * 4) // 2048 best_prior quarter blocks
#define BT_BPB 76            // ceil(P_/256) best_truth blocks per batch
#define NJ 38                // ceil(P_/512) per-thread elements in k_ohem

__device__ __forceinline__ float sl1(float x) {
    float d = fabsf(x);
    return (d < 1.0f) ? 0.5f * d * d : d - 0.5f;
}

__device__ __forceinline__ float iou_gt_prior(float4 t, float4 pr) {
    float px1 = pr.x - pr.z * 0.5f;
    float py1 = pr.y - pr.w * 0.5f;
    float px2 = pr.x + pr.z * 0.5f;
    float py2 = pr.y + pr.w * 0.5f;
    float ltx = fmaxf(t.x, px1), lty = fmaxf(t.y, py1);
    float rbx = fminf(t.z, px2), rby = fminf(t.w, py2);
    float iw = fmaxf(rbx - ltx, 0.0f), ih = fmaxf(rby - lty, 0.0f);
    float inter = iw * ih;
    float area_t = (t.z - t.x) * (t.w - t.y);
    float area_p = (px2 - px1) * (py2 - py1);
    return inter / (area_t + area_p - inter);
}

// ---- parallel threshold pick (512 threads, 8 waves) ----
template <int PER>
__device__ __forceinline__ void pick_top(const int* __restrict__ h, int kk, int tid,
                                         int* s_bin, int* s_kk, int* wsum) {
    const int lane = tid & 63, wid = tid >> 6;
    const int base = tid * PER;
    int v[PER]; int s = 0;
    #pragma unroll
    for (int j = 0; j < PER; ++j) { v[j] = h[base + j]; s += v[j]; }
    int x = s;                                  // inclusive suffix scan in wave
    #pragma unroll
    for (int d = 1; d < 64; d <<= 1) {
        int y = __shfl_down(x, d);
        if (lane + d < 64) x += y;
    }
    if (lane == 0) wsum[wid] = x;
    __syncthreads();
    int above = 0;
    #pragma unroll
    for (int w = 0; w < 8; ++w) if (w > wid) above += wsum[w];
    int T = (x - s) + above;
    if (T < kk && kk <= T + s) {                // exactly one thread true
        int kl = kk - T, cum = 0;
        #pragma unroll
        for (int j = PER - 1; j >= 0; --j) {
            if (cum + v[j] >= kl) { *s_bin = base + j; *s_kk = kl - cum; break; }
            cum += v[j];
        }
    }
    __syncthreads();
}

template <int PER>
__device__ __forceinline__ void pick_bot(const int* __restrict__ h, int kk, int tid,
                                         int* s_bin, int* s_kk, int* wsum) {
    const int lane = tid & 63, wid = tid >> 6;
    const int base = tid * PER;
    int v[PER]; int s = 0;
    #pragma unroll
    for (int j = 0; j < PER; ++j) { v[j] = h[base + j]; s += v[j]; }
    int x = s;                                  // inclusive prefix scan in wave
    #pragma unroll
    for (int d = 1; d < 64; d <<= 1) {
        int y = __shfl_up(x, d);
        if (lane >= d) x += y;
    }
    if (lane == 63) wsum[wid] = x;
    __syncthreads();
    int below = 0;
    #pragma unroll
    for (int w = 0; w < 8; ++w) if (w < wid) below += wsum[w];
    int T = (x - s) + below;
    if (T < kk && kk <= T + s) {
        int kl = kk - T, cum = 0;
        #pragma unroll
        for (int j = 0; j < PER; ++j) {
            if (cum + v[j] >= kl) { *s_bin = base + j; *s_kk = kl - cum; break; }
            cum += v[j];
        }
    }
    __syncthreads();
}

// Merged matcher.
// Blocks [0, 2048): best_prior quarters — (b,o) argmax over P_/4 priors,
//   merged globally via atomicMax on key = fbits(iou)<<32 | ~p (max value,
//   smallest-p tie-break == numpy argmax). best_key pre-zeroed by memset.
// Blocks [2048, 2048+1216): best_truth — per-prior max/argmax over O gts.
__global__ void k_match(const float* __restrict__ priors,
                        const float* __restrict__ gt_boxes,
                        const int* __restrict__ gt_labels,
                        unsigned long long* __restrict__ best_key,
                        float* __restrict__ bt_ov,
                        int* __restrict__ bt_ix,
                        int* __restrict__ bt_lab) {
    const int bid = blockIdx.x;
    if (bid < BP_BLK) {
        // ---- best_prior quarter role ----
        int pair = bid >> 2, qtr = bid & 3;
        int b = pair >> 5, o = pair & 31;
        float4 t = ((const float4*)gt_boxes)[b * O_ + o];
        float bestv = -1.0f; int besti = 0;
        int pstart = qtr * PQ;
        for (int p = pstart + threadIdx.x; p < pstart + PQ; p += 256) {
            float4 pr = ((const float4*)priors)[p];
            float v = iou_gt_prior(t, pr);
            if (v > bestv) { bestv = v; besti = p; }
        }
        __shared__ float sv[256];
        __shared__ int   si[256];
        sv[threadIdx.x] = bestv; si[threadIdx.x] = besti;
        __syncthreads();
        for (int s = 128; s > 0; s >>= 1) {
            if (threadIdx.x < s) {
                float ov = sv[threadIdx.x + s]; int oi = si[threadIdx.x + s];
                if (ov > sv[threadIdx.x] ||
                    (ov == sv[threadIdx.x] && oi < si[threadIdx.x])) {
                    sv[threadIdx.x] = ov; si[threadIdx.x] = oi;
                }
            }
            __syncthreads();
        }
        if (threadIdx.x == 0) {
            unsigned long long key =
                ((unsigned long long)__float_as_uint(sv[0]) << 32) |
                (unsigned long long)(0xFFFFFFFFu - (unsigned int)si[0]);
            atomicMax(&best_key[pair], key);
        }
    } else {
        // ---- best_truth role ----
        int idx = bid - BP_BLK;
        int b = idx / BT_BPB;
        int p = (idx % BT_BPB) * 256 + threadIdx.x;
        __shared__ float4 gt[O_];
        __shared__ int    gl[O_];
        if (threadIdx.x < O_) {
            gt[threadIdx.x] = ((const float4*)gt_boxes)[b * O_ + threadIdx.x];
            gl[threadIdx.x] = gt_labels[b * O_ + threadIdx.x];
        }
        __syncthreads();
        if (p >= P_) return;
        float4 pr = ((const float4*)priors)[p];
        float bestv = -1.0f; int besti = 0;
        for (int o = 0; o < O_; ++o) {
            float v = iou_gt_prior(gt[o], pr);
            if (v > bestv) { bestv = v; besti = o; }
        }
        size_t bp = (size_t)b * P_ + p;
        bt_ov[bp] = bestv;
        bt_ix[bp] = besti;
        bt_lab[bp] = gl[besti];
    }
}

// Force-match (numpy last-wins scatter: serial per batch via leader lane +
// shfl) + zero the accumulators consumed downstream.
__global__ void k_force(const unsigned long long* __restrict__ best_key,
                        const int* __restrict__ gt_labels,
                        float* __restrict__ bt_ov,
                        int* __restrict__ bt_ix,
                        int* __restrict__ bt_lab,
                        int* __restrict__ num_pos,
                        float* __restrict__ accum,
                        int* __restrict__ done) {
    const int tid = threadIdx.x;          // 512 = 16 batches x 32 gts
    const int b = tid >> 5, o = tid & 31;
    unsigned long long key = best_key[b * O_ + o];
    int p  = (int)(0xFFFFFFFFu - (unsigned int)(key & 0xFFFFFFFFu));
    int ll = gt_labels[b * O_ + o];
    if (tid < B_) num_pos[tid] = 0;
    if (tid == 0) { accum[0] = 0.0f; accum[1] = 0.0f; *done = 0; }
    const int lanebase = tid & 32;        // batch's base lane within the wave
    for (int oo = 0; oo < O_; ++oo) {
        int pp = __shfl(p, lanebase + oo);
        int l2 = __shfl(ll, lanebase + oo);
        if (o == 0) {
            size_t idx = (size_t)b * P_ + pp;
            bt_ov[idx] = 2.0f;
            bt_ix[idx] = oo;
            bt_lab[idx] = l2;
        }
    }
}

// Main pass (R6-verified structure, 76us): 512 threads stage 128 rows
// (41.5KB LDS) via coalesced float4, then 4 threads/row logsumexp with two
// shfl_xor combines. Dual num_pos counters fix batch-boundary attribution
// (19248 % 128 != 0 -> a tile can span 2 batches).
__global__ __launch_bounds__(TPB, 6) void
k_main(const float* __restrict__ loc_data,
       const float* __restrict__ conf_data,
       const float* __restrict__ priors,
       const float* __restrict__ gt_boxes,
       const float* __restrict__ bt_ov,
       const int* __restrict__ bt_ix,
       const int* __restrict__ bt_lab,
       float* __restrict__ lossc,
       float* __restrict__ ce_neg,
       int* __restrict__ num_pos,
       float* __restrict__ accum) {
    __shared__ float srow[RPB * C_];      // 41472 B
    __shared__ float s_lB, s_ceP;
    __shared__ int s_np0, s_np1;
    const int row0 = blockIdx.x * RPB;
    const int tid = threadIdx.x;
    if (tid == 0) { s_lB = 0.0f; s_ceP = 0.0f; s_np0 = 0; s_np1 = 0; }

    {   // stage: 2592 float4 = RPB*C_/4; 5 full rounds + 32-lane tail
        const float4* src = (const float4*)(conf_data + (size_t)row0 * C_);
        float4* dst = (float4*)srow;
        float4 t0 = src[tid];
        float4 t1 = src[tid + 512];
        float4 t2 = src[tid + 1024];
        float4 t3 = src[tid + 1536];
        float4 t4 = src[tid + 2048];
        float4 t5;
        if (tid < 32) t5 = src[tid + 2560];
        dst[tid]        = t0;
        dst[tid + 512]  = t1;
        dst[tid + 1024] = t2;
        dst[tid + 1536] = t3;
        dst[tid + 2048] = t4;
        if (tid < 32) dst[tid + 2560] = t5;
    }
    __syncthreads();

    const int r = tid >> 2;               // row within tile
    const int q = tid & 3;                // sub-row worker
    const int bp = row0 + r;
    const int b = bp / P_;
    const int b0 = row0 / P_;
    const int p = bp - b * P_;
    const float* row = srow + r * C_;
    const int j0 = 20 * q;

    float ma = row[j0], mb = row[j0 + 1], mc = row[j0 + 2], md = row[j0 + 3];
    #pragma unroll
    for (int i = 4; i < 20; i += 4) {
        ma = fmaxf(ma, row[j0 + i]);     mb = fmaxf(mb, row[j0 + i + 1]);
        mc = fmaxf(mc, row[j0 + i + 2]); md = fmaxf(md, row[j0 + i + 3]);
    }
    float m = fmaxf(fmaxf(ma, mb), fmaxf(mc, md));
    if (q == 3) m = fmaxf(m, row[80]);
    m = fmaxf(m, __shfl_xor(m, 1));
    m = fmaxf(m, __shfl_xor(m, 2));

    float sa = 0.f, sb = 0.f, sc = 0.f, sd = 0.f;
    #pragma unroll
    for (int i = 0; i < 20; i += 4) {
        sa += __expf(row[j0 + i] - m);     sb += __expf(row[j0 + i + 1] - m);
        sc += __expf(row[j0 + i + 2] - m); sd += __expf(row[j0 + i + 3] - m);
    }
    float s = (sa + sb) + (sc + sd);
    if (q == 3) s += __expf(row[80] - m);
    s += __shfl_xor(s, 1);
    s += __shfl_xor(s, 2);
    float logZ = m + __logf(s);

    if (q == 0) {
        float ov = bt_ov[bp];
        int lab = bt_lab[bp];
        int conf_t = lab + 1;
        if (ov < POS_TH) conf_t = -1;
        if (ov < NEG_TH) conf_t = 0;
        bool pos = conf_t > 0;

        float lc = (pos || conf_t < 0) ? 0.0f : (logZ - row[0]);
        int cls = pos ? conf_t : 0;
        float ce = logZ - row[cls];

        lossc[bp] = lc;
        ce_neg[bp] = (conf_t == 0) ? ce : 0.0f;

        if (pos) {
            int ti = bt_ix[bp];
            float4 t = ((const float4*)gt_boxes)[b * O_ + ti];
            float4 pr = ((const float4*)priors)[p];
            float mcx = (t.x + t.z) * 0.5f;
            float mcy = (t.y + t.w) * 0.5f;
            float gx = (mcx - pr.x) / (0.1f * pr.z);
            float gy = (mcy - pr.y) / (0.1f * pr.w);
            float gw = logf((t.z - t.x) / pr.z) / 0.2f;
            float gh = logf((t.w - t.y) / pr.w) / 0.2f;
            float4 ld = ((const float4*)loc_data)[bp];
            float sc2 = sl1(ld.x - gx) + sl1(ld.y - gy) + sl1(ld.z - gw) + sl1(ld.w - gh);
            atomicAdd(&s_lB, sc2);
            atomicAdd(&s_ceP, ce);
            if (b == b0) atomicAdd(&s_np0, 1); else atomicAdd(&s_np1, 1);
        }
    }
    __syncthreads();
    if (tid == 0) {
        if (s_lB != 0.0f) atomicAdd(&accum[0], s_lB);
        if (s_ceP != 0.0f) atomicAdd(&accum[1], s_ceP);
        if (s_np0) atomicAdd(&num_pos[b0], s_np0);
        if (s_np1) atomicAdd(&num_pos[b0 + 1], s_np1);   // tile spans <=2 batches
    }
}

// One block per batch: register-cached radix select (exact stable-argsort
// semantics); last block folds the final scalars and writes out[2].
__global__ __launch_bounds__(512) void
k_ohem(const float* __restrict__ lossc, const float* __restrict__ ce_neg,
       const int* __restrict__ num_pos, const float* __restrict__ accum,
       float* __restrict__ ce_sum, int* __restrict__ done,
       float* __restrict__ out) {
    const int b = blockIdx.x;
    const int tid = threadIdx.x;
    const float* lc = lossc + (size_t)b * P_;
    const float* cn = ce_neg + (size_t)b * P_;
    __shared__ int h[2048];
    __shared__ int wsum[8];
    __shared__ int s_bin, s_kk;
    __shared__ float red[512];

    int k = 3 * num_pos[b];
    if (k > P_ - 1) k = P_ - 1;

    float result = 0.0f;
    if (k > 0) {
        unsigned int fb[NJ]; float cv[NJ];
        #pragma unroll
        for (int j = 0; j < NJ; ++j) {
            int i = tid + j * 512;
            bool valid = (i < P_);
            fb[j] = valid ? __float_as_uint(lc[i]) : 0xFFFFFFFFu;
            cv[j] = valid ? cn[i] : 0.0f;
        }
        // round 0: 1024-bin hist of fb>>21 (monotone, lossc >= 0)
        for (int i = tid; i < 2048; i += 512) h[i] = 0;
        __syncthreads();
        #pragma unroll
        for (int j = 0; j < NJ; ++j) atomicAdd(&h[fb[j] >> 21], 1);
        __syncthreads();
        pick_top<2>(h, k, tid, &s_bin, &s_kk, wsum);
        const unsigned int T = (unsigned int)s_bin;
        int kk = s_kk;

        // pass A: sum ce for bins > T; hist bits 20..10 of bin==T
        for (int i = tid; i < 2048; i += 512) h[i] = 0;
        __syncthreads();
        float sum = 0.0f;
        #pragma unroll
        for (int j = 0; j < NJ; ++j) {
            unsigned int bin = fb[j] >> 21;
            if (bin > T) sum += cv[j];                 // sentinel adds 0
            else if (bin == T) atomicAdd(&h[(fb[j] >> 10) & 2047], 1);
        }
        __syncthreads();
        pick_top<4>(h, kk, tid, &s_bin, &s_kk, wsum);
        const unsigned int pre21 = (T << 11) | (unsigned int)s_bin;
        kk = s_kk;

        // pass B: hist bits 9..0 of elements matching top 22 bits
        for (int i = tid; i < 1024; i += 512) h[i] = 0;
        __syncthreads();
        #pragma unroll
        for (int j = 0; j < NJ; ++j)
            if ((fb[j] >> 10) == pre21) atomicAdd(&h[fb[j] & 1023], 1);
        __syncthreads();
        pick_top<2>(h, kk, tid, &s_bin, &s_kk, wsum);
        const unsigned int V = (pre21 << 10) | (unsigned int)s_bin;
        const int ee = h[s_bin];
        kk = s_kk;

        if (kk == ee) {
            #pragma unroll
            for (int j = 0; j < NJ; ++j)
                if ((fb[j] >> 21) == T && fb[j] >= V) sum += cv[j];
        } else {
            // kk smallest-index elements with fb == V (stable argsort ties)
            for (int i = tid; i < 512; i += 512) h[i] = 0;
            __syncthreads();
            #pragma unroll
            for (int j = 0; j < NJ; ++j)
                if (fb[j] == V) atomicAdd(&h[(tid + j * 512) >> 6], 1);
            __syncthreads();
            pick_bot<1>(h, kk, tid, &s_bin, &s_kk, wsum);
            const int d6 = s_bin;
            kk = s_kk;
            h[tid] = 0;
            __syncthreads();
            #pragma unroll
            for (int j = 0; j < NJ; ++j) {
                int i = tid + j * 512;
                if (fb[j] == V && (i >> 6) == d6) atomicAdd(&h[i & 63], 1);
            }
            __syncthreads();
            pick_bot<1>(h, kk, tid, &s_bin, &s_kk, wsum);
            const int Istar = (d6 << 6) | s_bin;
            #pragma unroll
            for (int j = 0; j < NJ; ++j) {
                int i = tid + j * 512;
                if ((fb[j] >> 21) == T && (fb[j] > V || (fb[j] == V && i <= Istar)))
                    sum += cv[j];
            }
        }

        red[tid] = sum;
        __syncthreads();
        for (int s = 256; s > 0; s >>= 1) {
            if (tid < s) red[tid] += red[tid + s];
            __syncthreads();
        }
        result = red[0];
    }

    if (tid == 0) {
        ce_sum[b] = result;
        __threadfence();
        int old = atomicAdd(done, 1);
        if (old == B_ - 1) {                  // last block folds the output
            __threadfence();
            int tp = 0; float ns = 0.0f;
            for (int bb = 0; bb < B_; ++bb) { tp += num_pos[bb]; ns += ce_sum[bb]; }
            float inv = 1.0f / (float)tp;
            out[0] = accum[0] * 1.5f * inv;   // BBOX_ALPHA
            out[1] = (accum[1] + ns) * inv;   // CONF_ALPHA
        }
    }
}

extern "C" void kernel_launch(void* const* d_in, const int* in_sizes, int n_in,
                              void* d_out, int out_size, void* d_ws, size_t ws_size,
                              hipStream_t stream) {
    const float* loc    = (const float*)d_in[0];
    const float* conf   = (const float*)d_in[1];
    const float* priors = (const float*)d_in[2];
    const float* gtb    = (const float*)d_in[3];
    const int*   gtl    = (const int*)d_in[4];
    float* out = (float*)d_out;

    const size_t BP = (size_t)B_ * P_;
    float* W = (float*)d_ws;
    float* bt_ov   = W;
    float* lossc   = W + BP;
    float* ce_neg  = W + 2 * BP;
    int*   bt_ix   = (int*)(W + 3 * BP);
    int*   bt_lab  = (int*)(W + 4 * BP);
    unsigned long long* best_key = (unsigned long long*)(W + 5 * BP);  // 8B-aligned
    int*   num_pos = (int*)(best_key + B_ * O_);
    float* ce_sum  = (float*)(num_pos + B_);
    float* accum   = ce_sum + B_;
    int*   done    = (int*)(accum + 2);

    hipMemsetAsync(best_key, 0, B_ * O_ * sizeof(unsigned long long), stream);
    hipLaunchKernelGGL(k_match, dim3(BP_BLK + B_ * BT_BPB), dim3(256), 0, stream,
                       priors, gtb, gtl, best_key, bt_ov, bt_ix, bt_lab);
    hipLaunchKernelGGL(k_force, dim3(1), dim3(512), 0, stream,
                       best_key, gtl, bt_ov, bt_ix, bt_lab, num_pos, accum, done);
    hipLaunchKernelGGL(k_main, dim3((int)(BP / RPB)), dim3(TPB), 0, stream,
                       loc, conf, priors, gtb, bt_ov, bt_ix, bt_lab,
                       lossc, ce_neg, num_pos, accum);
    hipLaunchKernelGGL(k_ohem, dim3(B_), dim3(512), 0, stream,
                       lossc, ce_neg, num_pos, accum, ce_sum, done, out);
}